// Round 5
// baseline (438.871 us; speedup 1.0000x reference)
//
#include <hip/hip_runtime.h>
#include <hip/hip_bf16.h>

#define N_NODES 50000
#define N_EDGES 800000
#define HID 64
#define N_LAYERS 3
#define BN_EPS 1e-5f
#define SELF_W 2.0f
#define NB_SCAN 196   // ceil(50000/256)
#define FPSCALE 16777216.0f          // 2^24
#define FPINV   (1.0f / 16777216.0f)
#define MASK40  0xFFFFFFFFFFull

// ---------------- precompute kernels (graph-invariant) ----------------

// packed (cnt<<40 | fixed-point wsum) = 0; stats (3 layers x 128) = 0
__global__ void k_init(unsigned long long* __restrict__ packed, float* __restrict__ stats) {
    int i = blockIdx.x * blockDim.x + threadIdx.x;
    if (i < N_NODES) packed[i] = 0ull;
    if (i < N_LAYERS * 2 * HID) stats[i] = 0.f;
}

// one 64-bit atomic per edge; returned old count = rank of edge within its dst
__global__ void k_hist(const int* __restrict__ dst, const float* __restrict__ w,
                       unsigned long long* __restrict__ packed,
                       unsigned char* __restrict__ rank) {
    int e = blockIdx.x * blockDim.x + threadIdx.x;
    if (e < N_EDGES) {
        unsigned q = (unsigned)(w[e] * FPSCALE + 0.5f);
        unsigned long long old = atomicAdd(&packed[dst[e]], (1ull << 40) | (unsigned long long)q);
        rank[e] = (unsigned char)(old >> 40);
    }
}

// unpack packed -> dinv/selfnorm, and block-local exclusive scan of cnt -> rowptr
__global__ void k_scan1(const unsigned long long* __restrict__ packed,
                        float* __restrict__ dinv, float* __restrict__ selfnorm,
                        int* __restrict__ rowptr, int* __restrict__ partials) {
    __shared__ int sh[256];
    int tid = threadIdx.x;
    int i = blockIdx.x * 256 + tid;
    int v = 0;
    if (i < N_NODES) {
        unsigned long long p = packed[i];
        v = (int)(p >> 40);
        float deg = SELF_W + (float)(p & MASK40) * FPINV;
        float di = rsqrtf(deg);          // deg >= 2 always
        dinv[i] = di;
        selfnorm[i] = SELF_W * di * di;
    }
    sh[tid] = v;
    __syncthreads();
    for (int off = 1; off < 256; off <<= 1) {
        int t = (tid >= off) ? sh[tid - off] : 0;
        __syncthreads();
        sh[tid] += t;
        __syncthreads();
    }
    if (i < N_NODES) rowptr[i] = sh[tid] - v;
    if (tid == 255) partials[blockIdx.x] = sh[255];
}

__global__ void k_scan2(int* __restrict__ partials) {
    __shared__ int sh[256];
    int tid = threadIdx.x;
    int v = (tid < NB_SCAN) ? partials[tid] : 0;
    sh[tid] = v;
    __syncthreads();
    for (int off = 1; off < 256; off <<= 1) {
        int t = (tid >= off) ? sh[tid - off] : 0;
        __syncthreads();
        sh[tid] += t;
        __syncthreads();
    }
    if (tid < NB_SCAN) partials[tid] = sh[tid] - v;
}

__global__ void k_scan3(int* __restrict__ rowptr, const int* __restrict__ partials) {
    int i = blockIdx.x * 256 + threadIdx.x;
    if (i < N_NODES) rowptr[i] += partials[blockIdx.x];
    if (blockIdx.x == 0 && threadIdx.x == 0) rowptr[N_NODES] = N_EDGES;
}

// CSR fill, atomic-free: pos = rowptr[dst] + rank[e]
// entry = (bf16(norm) << 16) | src   (src < 65536, norm < 0.5)
__global__ void k_fill(const int* __restrict__ src, const int* __restrict__ dst,
                       const float* __restrict__ w, const float* __restrict__ dinv,
                       const unsigned char* __restrict__ rank,
                       const int* __restrict__ rowptr, unsigned* __restrict__ entries) {
    int e = blockIdx.x * blockDim.x + threadIdx.x;
    if (e < N_EDGES) {
        int s = src[e], d = dst[e];
        float n = dinv[s] * w[e] * dinv[d];
        unsigned nb = (__float_as_uint(n) + 0x8000u) & 0xFFFF0000u;  // round-to-nearest bf16
        int pos = rowptr[d] + (int)rank[e];
        entries[pos] = nb | (unsigned)s;
    }
}

// ---------------- per-layer kernels ----------------

// lin = h @ W   (layer 0 only; 256 thr = 4 rows x 64 cols; W staged in LDS)
__global__ void k_linear(const float* __restrict__ h, const float* __restrict__ W,
                         float* __restrict__ lin) {
    __shared__ float sW[HID * HID];
    __shared__ float sh[4][HID];
    int tid = threadIdx.x;
    for (int k = tid; k < HID * HID; k += 256) sW[k] = W[k];
    int r = tid >> 6, c = tid & 63;
    int row = blockIdx.x * 4 + r;
    if (row < N_NODES) sh[r][c] = h[(size_t)row * HID + c];
    __syncthreads();
    if (row < N_NODES) {
        float acc = 0.f;
#pragma unroll
        for (int k = 0; k < HID; ++k) acc = fmaf(sh[r][k], sW[k * HID + c], acc);
        lin[(size_t)row * HID + c] = acc;
    }
}

// gather-aggregate + fused BN stats. Grid-stride: one wave per node per step.
// out = relu( selfnorm*lin[node] + sum_e norm_e * lin[src_e] + b )
// Entries for a node are loaded with ONE coalesced lane-load, then broadcast
// via __shfl (v_readlane) — no per-edge uniform VMEM loads.
__global__ void k_gather(const float* __restrict__ lin, const unsigned* __restrict__ entries,
                         const int* __restrict__ rowptr, const float* __restrict__ selfnorm,
                         const float* __restrict__ b, float* __restrict__ out,
                         float* __restrict__ stats) {
    int wslot = __builtin_amdgcn_readfirstlane((int)(threadIdx.x >> 6));
    int lane = threadIdx.x & 63;
    float bl = b[lane];
    float s1 = 0.f, s2 = 0.f;
    for (int node = blockIdx.x * 4 + wslot; node < N_NODES; node += gridDim.x * 4) {
        float acc = lin[(size_t)node * HID + lane] * selfnorm[node];
        int start = rowptr[node];
        int c = rowptr[node + 1] - start;
        for (int base = 0; base < c; base += 64) {
            unsigned e = entries[start + base + lane];   // padded; lanes >= rem read junk
            int m = c - base; if (m > 64) m = 64;
            int k = 0;
            for (; k + 3 < m; k += 4) {
                unsigned e0 = __shfl(e, k),     e1 = __shfl(e, k + 1);
                unsigned e2 = __shfl(e, k + 2), e3 = __shfl(e, k + 3);
                float v0 = lin[(size_t)(e0 & 0xFFFFu) * HID + lane];
                float v1 = lin[(size_t)(e1 & 0xFFFFu) * HID + lane];
                float v2 = lin[(size_t)(e2 & 0xFFFFu) * HID + lane];
                float v3 = lin[(size_t)(e3 & 0xFFFFu) * HID + lane];
                acc = fmaf(v0, __uint_as_float(e0 & 0xFFFF0000u), acc);
                acc = fmaf(v1, __uint_as_float(e1 & 0xFFFF0000u), acc);
                acc = fmaf(v2, __uint_as_float(e2 & 0xFFFF0000u), acc);
                acc = fmaf(v3, __uint_as_float(e3 & 0xFFFF0000u), acc);
            }
            for (; k < m; ++k) {
                unsigned e0 = __shfl(e, k);
                float v0 = lin[(size_t)(e0 & 0xFFFFu) * HID + lane];
                acc = fmaf(v0, __uint_as_float(e0 & 0xFFFF0000u), acc);
            }
        }
        float t = acc + bl;
        t = t > 0.f ? t : 0.f;
        out[(size_t)node * HID + lane] = t;
        s1 += t; s2 += t * t;
    }
    // block-level BN-stats reduce (all waves reach here)
    __shared__ float ls[4][HID], ls2[4][HID];
    ls[wslot][lane] = s1; ls2[wslot][lane] = s2;
    __syncthreads();
    if (threadIdx.x < HID) {
        int c = threadIdx.x;
        atomicAdd(&stats[c],       ls[0][c] + ls[1][c] + ls[2][c] + ls[3][c]);
        atomicAdd(&stats[HID + c], ls2[0][c] + ls2[1][c] + ls2[2][c] + ls2[3][c]);
    }
}

// fused: h_norm = BN(h) written in place, AND lin_next = h_norm @ W_next
__global__ void k_bnlin(float* __restrict__ h, const float* __restrict__ gamma,
                        const float* __restrict__ beta, const float* __restrict__ stats,
                        const float* __restrict__ W, float* __restrict__ lin) {
    __shared__ float sW[HID * HID];
    __shared__ float sh[4][HID];
    int tid = threadIdx.x;
    for (int k = tid; k < HID * HID; k += 256) sW[k] = W[k];
    int r = tid >> 6, c = tid & 63;
    const float invn = 1.0f / (float)N_NODES;
    float mu = stats[c] * invn;
    float var = stats[HID + c] * invn - mu * mu;
    float sc = rsqrtf(var + BN_EPS) * gamma[c];
    float sf = beta[c] - mu * sc;
    int row = blockIdx.x * 4 + r;
    float val = 0.f;
    if (row < N_NODES) {
        val = h[(size_t)row * HID + c] * sc + sf;
        h[(size_t)row * HID + c] = val;      // final normalized output
    }
    sh[r][c] = val;
    __syncthreads();
    if (row < N_NODES) {
        float acc = 0.f;
#pragma unroll
        for (int k = 0; k < HID; ++k) acc = fmaf(sh[r][k], sW[k * HID + c], acc);
        lin[(size_t)row * HID + c] = acc;
    }
}

// last layer: BN in place only
__global__ void k_bn_apply(float* __restrict__ h, const float* __restrict__ gamma,
                           const float* __restrict__ beta, const float* __restrict__ stats) {
    int idx = blockIdx.x * blockDim.x + threadIdx.x;
    if (idx < N_NODES * HID) {
        int c = idx & 63;
        const float invn = 1.0f / (float)N_NODES;
        float mu = stats[c] * invn;
        float var = stats[HID + c] * invn - mu * mu;
        float ivar = rsqrtf(var + BN_EPS);
        h[idx] = (h[idx] - mu) * ivar * gamma[c] + beta[c];
    }
}

// ---------------- launch ----------------

extern "C" void kernel_launch(void* const* d_in, const int* in_sizes, int n_in,
                              void* d_out, int out_size, void* d_ws, size_t ws_size,
                              hipStream_t stream) {
    const float* x      = (const float*)d_in[0];   // [N, 64]
    const int*   ei     = (const int*)d_in[1];     // [2, E] int32
    const float* w      = (const float*)d_in[2];   // [E]
    const float* Ws     = (const float*)d_in[3];   // [3, 64, 64]
    const float* bs     = (const float*)d_in[4];   // [3, 64]
    const float* gammas = (const float*)d_in[5];   // [3, 64]
    const float* betas  = (const float*)d_in[6];   // [3, 64]
    float* out = (float*)d_out;                    // [3, N, 64] fp32

    const int* src = ei;
    const int* dst = ei + N_EDGES;

    // workspace layout (8B-aligned items first)
    unsigned long long* packed = (unsigned long long*)d_ws;                 // N * 8B
    unsigned* entries = (unsigned*)(packed + N_NODES);                      // (E+64) * 4B
    float*  lin      = (float*)(entries + N_EDGES + 64);                    // N*64
    float*  dinv     = lin + (size_t)N_NODES * HID;                         // N
    float*  selfnorm = dinv + N_NODES;                                      // N
    int*    rowptr   = (int*)(selfnorm + N_NODES);                          // N+1
    int*    partials = rowptr + N_NODES + 1;                                // 256
    float*  stats    = (float*)(partials + 256);                            // 3 * 128
    unsigned char* rank = (unsigned char*)(stats + N_LAYERS * 2 * HID);     // E bytes

    const int T = 256;
    const int gN = (N_NODES + T - 1) / T;                     // 196
    const int gE = (N_EDGES + T - 1) / T;                     // 3125
    const int gR = (N_NODES + 3) / 4;                         // 12500
    const int gG = 2048;                                      // grid-stride gather
    const int gA = (N_NODES * HID + T - 1) / T;               // 12500

    // ---- graph-invariant precompute ----
    k_init<<<gN, T, 0, stream>>>(packed, stats);
    k_hist<<<gE, T, 0, stream>>>(dst, w, packed, rank);
    k_scan1<<<NB_SCAN, T, 0, stream>>>(packed, dinv, selfnorm, rowptr, partials);
    k_scan2<<<1, T, 0, stream>>>(partials);
    k_scan3<<<NB_SCAN, T, 0, stream>>>(rowptr, partials);
    k_fill<<<gE, T, 0, stream>>>(src, dst, w, dinv, rank, rowptr, entries);

    // ---- layers ----
    k_linear<<<gR, T, 0, stream>>>(x, Ws, lin);   // lin_0 = x @ W0
    for (int L = 0; L < N_LAYERS; ++L) {
        float* outL = out + (size_t)L * N_NODES * HID;
        const float* b  = bs + (size_t)L * HID;
        const float* g  = gammas + (size_t)L * HID;
        const float* bt = betas + (size_t)L * HID;
        float* statsL = stats + (size_t)L * 2 * HID;

        k_gather<<<gG, T, 0, stream>>>(lin, entries, rowptr, selfnorm, b, outL, statsL);
        if (L < N_LAYERS - 1) {
            const float* Wn = Ws + (size_t)(L + 1) * HID * HID;
            k_bnlin<<<gR, T, 0, stream>>>(outL, g, bt, statsL, Wn, lin);
        } else {
            k_bn_apply<<<gA, T, 0, stream>>>(outL, g, bt, statsL);
        }
    }
}

// Round 6
// 309.683 us; speedup vs baseline: 1.4172x; 1.4172x over previous
//
#include <hip/hip_runtime.h>
#include <hip/hip_bf16.h>

#define N_NODES 50000
#define N_EDGES 800000
#define HID 64
#define N_LAYERS 3
#define BN_EPS 1e-5f
#define SELF_W 2.0f
#define NB_SCAN 196   // ceil(50000/256)
#define FPSCALE 16777216.0f          // 2^24
#define FPINV   (1.0f / 16777216.0f)
#define MASK40  0xFFFFFFFFFFull

// ---------------- precompute kernels (graph-invariant) ----------------

// packed (cnt<<40 | fixed-point wsum) = 0; stats (3 layers x 128) = 0
__global__ void k_init(unsigned long long* __restrict__ packed, float* __restrict__ stats) {
    int i = blockIdx.x * blockDim.x + threadIdx.x;
    if (i < N_NODES) packed[i] = 0ull;
    if (i < N_LAYERS * 2 * HID) stats[i] = 0.f;
}

// one 64-bit atomic per edge; returned old count = rank of edge within its dst
__global__ void k_hist(const int* __restrict__ dst, const float* __restrict__ w,
                       unsigned long long* __restrict__ packed,
                       unsigned char* __restrict__ rank) {
    int e = blockIdx.x * blockDim.x + threadIdx.x;
    if (e < N_EDGES) {
        unsigned q = (unsigned)(w[e] * FPSCALE + 0.5f);
        unsigned long long old = atomicAdd(&packed[dst[e]], (1ull << 40) | (unsigned long long)q);
        rank[e] = (unsigned char)(old >> 40);
    }
}

// unpack packed -> dinv/selfnorm, and block-local exclusive scan of cnt -> rowptr
__global__ void k_scan1(const unsigned long long* __restrict__ packed,
                        float* __restrict__ dinv, float* __restrict__ selfnorm,
                        int* __restrict__ rowptr, int* __restrict__ partials) {
    __shared__ int sh[256];
    int tid = threadIdx.x;
    int i = blockIdx.x * 256 + tid;
    int v = 0;
    if (i < N_NODES) {
        unsigned long long p = packed[i];
        v = (int)(p >> 40);
        float deg = SELF_W + (float)(p & MASK40) * FPINV;
        float di = rsqrtf(deg);          // deg >= 2 always
        dinv[i] = di;
        selfnorm[i] = SELF_W * di * di;
    }
    sh[tid] = v;
    __syncthreads();
    for (int off = 1; off < 256; off <<= 1) {
        int t = (tid >= off) ? sh[tid - off] : 0;
        __syncthreads();
        sh[tid] += t;
        __syncthreads();
    }
    if (i < N_NODES) rowptr[i] = sh[tid] - v;
    if (tid == 255) partials[blockIdx.x] = sh[255];
}

__global__ void k_scan2(int* __restrict__ partials) {
    __shared__ int sh[256];
    int tid = threadIdx.x;
    int v = (tid < NB_SCAN) ? partials[tid] : 0;
    sh[tid] = v;
    __syncthreads();
    for (int off = 1; off < 256; off <<= 1) {
        int t = (tid >= off) ? sh[tid - off] : 0;
        __syncthreads();
        sh[tid] += t;
        __syncthreads();
    }
    if (tid < NB_SCAN) partials[tid] = sh[tid] - v;
}

__global__ void k_scan3(int* __restrict__ rowptr, const int* __restrict__ partials) {
    int i = blockIdx.x * 256 + threadIdx.x;
    if (i < N_NODES) rowptr[i] += partials[blockIdx.x];
    if (blockIdx.x == 0 && threadIdx.x == 0) rowptr[N_NODES] = N_EDGES;
}

// CSR fill, atomic-free: pos = rowptr[dst] + rank[e]
// entry = (bf16(norm) high 16) | src   (src < 65536, norm < 0.5)
__global__ void k_fill(const int* __restrict__ src, const int* __restrict__ dst,
                       const float* __restrict__ w, const float* __restrict__ dinv,
                       const unsigned char* __restrict__ rank,
                       const int* __restrict__ rowptr, unsigned* __restrict__ entries) {
    int e = blockIdx.x * blockDim.x + threadIdx.x;
    if (e < N_EDGES) {
        int s = src[e], d = dst[e];
        float n = dinv[s] * w[e] * dinv[d];
        unsigned nb = (__float_as_uint(n) + 0x8000u) & 0xFFFF0000u;  // round-to-nearest bf16
        int pos = rowptr[d] + (int)rank[e];
        entries[pos] = nb | (unsigned)s;
    }
}

// ---------------- per-layer kernels ----------------

// lin = h @ W   (layer 0 only; 256 thr = 4 rows x 64 cols; W staged in LDS)
__global__ void k_linear(const float* __restrict__ h, const float* __restrict__ W,
                         float* __restrict__ lin) {
    __shared__ float sW[HID * HID];
    __shared__ float sh[4][HID];
    int tid = threadIdx.x;
    for (int k = tid; k < HID * HID; k += 256) sW[k] = W[k];
    int r = tid >> 6, c = tid & 63;
    int row = blockIdx.x * 4 + r;
    if (row < N_NODES) sh[r][c] = h[(size_t)row * HID + c];
    __syncthreads();
    if (row < N_NODES) {
        float acc = 0.f;
#pragma unroll
        for (int k = 0; k < HID; ++k) acc = fmaf(sh[r][k], sW[k * HID + c], acc);
        lin[(size_t)row * HID + c] = acc;
    }
}

// gather-aggregate: one wave per node, lane = feature. Entry loads are
// wave-uniform -> scalar path (s_load); 8 independent lin-row gathers in flight.
// out = relu( selfnorm*lin[node] + sum_e norm_e * lin[src_e] + b )
__global__ void k_gather(const float* __restrict__ lin, const unsigned* __restrict__ entries,
                         const int* __restrict__ rowptr, const float* __restrict__ selfnorm,
                         const float* __restrict__ b, float* __restrict__ out) {
    int wslot = __builtin_amdgcn_readfirstlane((int)(threadIdx.x >> 6));
    int node = blockIdx.x * 4 + wslot;
    int lane = threadIdx.x & 63;
    if (node >= N_NODES) return;
    float bl = b[lane];
    float acc = lin[(size_t)node * HID + lane] * selfnorm[node];
    int start = rowptr[node];
    int c = rowptr[node + 1] - start;
    const unsigned* ep = entries + start;
    int k = 0;
    for (; k + 7 < c; k += 8) {
        unsigned e0 = ep[k],     e1 = ep[k + 1], e2 = ep[k + 2], e3 = ep[k + 3];
        unsigned e4 = ep[k + 4], e5 = ep[k + 5], e6 = ep[k + 6], e7 = ep[k + 7];
        float v0 = lin[(size_t)(e0 & 0xFFFFu) * HID + lane];
        float v1 = lin[(size_t)(e1 & 0xFFFFu) * HID + lane];
        float v2 = lin[(size_t)(e2 & 0xFFFFu) * HID + lane];
        float v3 = lin[(size_t)(e3 & 0xFFFFu) * HID + lane];
        float v4 = lin[(size_t)(e4 & 0xFFFFu) * HID + lane];
        float v5 = lin[(size_t)(e5 & 0xFFFFu) * HID + lane];
        float v6 = lin[(size_t)(e6 & 0xFFFFu) * HID + lane];
        float v7 = lin[(size_t)(e7 & 0xFFFFu) * HID + lane];
        acc = fmaf(v0, __uint_as_float(e0 & 0xFFFF0000u), acc);
        acc = fmaf(v1, __uint_as_float(e1 & 0xFFFF0000u), acc);
        acc = fmaf(v2, __uint_as_float(e2 & 0xFFFF0000u), acc);
        acc = fmaf(v3, __uint_as_float(e3 & 0xFFFF0000u), acc);
        acc = fmaf(v4, __uint_as_float(e4 & 0xFFFF0000u), acc);
        acc = fmaf(v5, __uint_as_float(e5 & 0xFFFF0000u), acc);
        acc = fmaf(v6, __uint_as_float(e6 & 0xFFFF0000u), acc);
        acc = fmaf(v7, __uint_as_float(e7 & 0xFFFF0000u), acc);
    }
    for (; k + 1 < c; k += 2) {
        unsigned e0 = ep[k], e1 = ep[k + 1];
        float v0 = lin[(size_t)(e0 & 0xFFFFu) * HID + lane];
        float v1 = lin[(size_t)(e1 & 0xFFFFu) * HID + lane];
        acc = fmaf(v0, __uint_as_float(e0 & 0xFFFF0000u), acc);
        acc = fmaf(v1, __uint_as_float(e1 & 0xFFFF0000u), acc);
    }
    if (k < c) {
        unsigned e0 = ep[k];
        float v0 = lin[(size_t)(e0 & 0xFFFFu) * HID + lane];
        acc = fmaf(v0, __uint_as_float(e0 & 0xFFFF0000u), acc);
    }
    float t = acc + bl;
    out[(size_t)node * HID + lane] = t > 0.f ? t : 0.f;
}

// per-column sum/sumsq of h (already relu'd)
__global__ void k_bn_stats(const float* __restrict__ h, float* __restrict__ stats) {
    int c = threadIdx.x & 63, rr = threadIdx.x >> 6;
    float s = 0.f, s2 = 0.f;
    for (int row = blockIdx.x * 4 + rr; row < N_NODES; row += gridDim.x * 4) {
        float t = h[(size_t)row * HID + c];
        s += t; s2 += t * t;
    }
    __shared__ float ls[4][HID], ls2[4][HID];
    ls[rr][c] = s; ls2[rr][c] = s2;
    __syncthreads();
    if (threadIdx.x < HID) {
        atomicAdd(&stats[c],       ls[0][c] + ls[1][c] + ls[2][c] + ls[3][c]);
        atomicAdd(&stats[HID + c], ls2[0][c] + ls2[1][c] + ls2[2][c] + ls2[3][c]);
    }
}

// fused: h_norm = BN(h) written in place, AND lin_next = h_norm @ W_next
__global__ void k_bnlin(float* __restrict__ h, const float* __restrict__ gamma,
                        const float* __restrict__ beta, const float* __restrict__ stats,
                        const float* __restrict__ W, float* __restrict__ lin) {
    __shared__ float sW[HID * HID];
    __shared__ float sh[4][HID];
    int tid = threadIdx.x;
    for (int k = tid; k < HID * HID; k += 256) sW[k] = W[k];
    int r = tid >> 6, c = tid & 63;
    const float invn = 1.0f / (float)N_NODES;
    float mu = stats[c] * invn;
    float var = stats[HID + c] * invn - mu * mu;
    float sc = rsqrtf(var + BN_EPS) * gamma[c];
    float sf = beta[c] - mu * sc;
    int row = blockIdx.x * 4 + r;
    float val = 0.f;
    if (row < N_NODES) {
        val = h[(size_t)row * HID + c] * sc + sf;
        h[(size_t)row * HID + c] = val;      // final normalized output
    }
    sh[r][c] = val;
    __syncthreads();
    if (row < N_NODES) {
        float acc = 0.f;
#pragma unroll
        for (int k = 0; k < HID; ++k) acc = fmaf(sh[r][k], sW[k * HID + c], acc);
        lin[(size_t)row * HID + c] = acc;
    }
}

// last layer: BN in place only
__global__ void k_bn_apply(float* __restrict__ h, const float* __restrict__ gamma,
                           const float* __restrict__ beta, const float* __restrict__ stats) {
    int idx = blockIdx.x * blockDim.x + threadIdx.x;
    if (idx < N_NODES * HID) {
        int c = idx & 63;
        const float invn = 1.0f / (float)N_NODES;
        float mu = stats[c] * invn;
        float var = stats[HID + c] * invn - mu * mu;
        float ivar = rsqrtf(var + BN_EPS);
        h[idx] = (h[idx] - mu) * ivar * gamma[c] + beta[c];
    }
}

// ---------------- launch ----------------

extern "C" void kernel_launch(void* const* d_in, const int* in_sizes, int n_in,
                              void* d_out, int out_size, void* d_ws, size_t ws_size,
                              hipStream_t stream) {
    const float* x      = (const float*)d_in[0];   // [N, 64]
    const int*   ei     = (const int*)d_in[1];     // [2, E] int32
    const float* w      = (const float*)d_in[2];   // [E]
    const float* Ws     = (const float*)d_in[3];   // [3, 64, 64]
    const float* bs     = (const float*)d_in[4];   // [3, 64]
    const float* gammas = (const float*)d_in[5];   // [3, 64]
    const float* betas  = (const float*)d_in[6];   // [3, 64]
    float* out = (float*)d_out;                    // [3, N, 64] fp32

    const int* src = ei;
    const int* dst = ei + N_EDGES;

    // workspace layout (8B-aligned items first)
    unsigned long long* packed = (unsigned long long*)d_ws;                 // N * 8B
    unsigned* entries = (unsigned*)(packed + N_NODES);                      // (E+64) * 4B
    float*  lin      = (float*)(entries + N_EDGES + 64);                    // N*64
    float*  dinv     = lin + (size_t)N_NODES * HID;                         // N
    float*  selfnorm = dinv + N_NODES;                                      // N
    int*    rowptr   = (int*)(selfnorm + N_NODES);                          // N+1
    int*    partials = rowptr + N_NODES + 1;                                // 256
    float*  stats    = (float*)(partials + 256);                            // 3 * 128
    unsigned char* rank = (unsigned char*)(stats + N_LAYERS * 2 * HID);     // E bytes

    const int T = 256;
    const int gN = (N_NODES + T - 1) / T;                     // 196
    const int gE = (N_EDGES + T - 1) / T;                     // 3125
    const int gR = (N_NODES + 3) / 4;                         // 12500
    const int gA = (N_NODES * HID + T - 1) / T;               // 12500

    // ---- graph-invariant precompute ----
    k_init<<<gN, T, 0, stream>>>(packed, stats);
    k_hist<<<gE, T, 0, stream>>>(dst, w, packed, rank);
    k_scan1<<<NB_SCAN, T, 0, stream>>>(packed, dinv, selfnorm, rowptr, partials);
    k_scan2<<<1, T, 0, stream>>>(partials);
    k_scan3<<<NB_SCAN, T, 0, stream>>>(rowptr, partials);
    k_fill<<<gE, T, 0, stream>>>(src, dst, w, dinv, rank, rowptr, entries);

    // ---- layers ----
    k_linear<<<gR, T, 0, stream>>>(x, Ws, lin);   // lin_0 = x @ W0
    for (int L = 0; L < N_LAYERS; ++L) {
        float* outL = out + (size_t)L * N_NODES * HID;
        const float* b  = bs + (size_t)L * HID;
        const float* g  = gammas + (size_t)L * HID;
        const float* bt = betas + (size_t)L * HID;
        float* statsL = stats + (size_t)L * 2 * HID;

        k_gather<<<gR, T, 0, stream>>>(lin, entries, rowptr, selfnorm, b, outL);
        k_bn_stats<<<256, T, 0, stream>>>(outL, statsL);
        if (L < N_LAYERS - 1) {
            const float* Wn = Ws + (size_t)(L + 1) * HID * HID;
            k_bnlin<<<gR, T, 0, stream>>>(outL, g, bt, statsL, Wn, lin);
        } else {
            k_bn_apply<<<gA, T, 0, stream>>>(outL, g, bt, statsL);
        }
    }
}